// Round 6
// baseline (554.574 us; speedup 1.0000x reference)
//
#include <hip/hip_runtime.h>

typedef unsigned short u16;
using bf16x8 = __attribute__((ext_vector_type(8))) short;
using f32x4  = __attribute__((ext_vector_type(4))) float;

static __device__ __forceinline__ u16 f2b(float f) {
  unsigned int x = __builtin_bit_cast(unsigned int, f);
  unsigned int r = (x + 0x7fffu + ((x >> 16) & 1u)) >> 16;
  return (u16)r;
}
static __device__ __forceinline__ float fin(float x) { return (x != x) ? 0.f : x; }
static __device__ __forceinline__ float expclamp(float x) {
  return __expf(fminf(fmaxf(x, -80.f), 80.f));
}
// packed f32->bf16 RNE convert (same rounding as f2b)
static __device__ __forceinline__ unsigned cvt2(float lo, float hi) {
  unsigned r;
  asm("v_cvt_pk_bf16_f32 %0, %1, %2" : "=v"(r) : "v"(lo), "v"(hi));
  return r;
}

#define SCALE 0.04419417382415922f  // 1/sqrt(512)
#define MFMA16(a, b, c) __builtin_amdgcn_mfma_f32_16x16x32_bf16((a), (b), (c), 0, 0, 0)

// Memory plan (ws = 33,554,432 B exactly):
//   ws: K bf16 [8][2048][512] @0; Vt bf16 [8][512][2048] (V transposed) @16.78MB
//   d_out per fp32-row r (4096 B): [0,1024) Q bf16 stash (stride 2048 u16),
//   [1024,1040) denom partials f32 x4 (slots 256..259) for column i=r%2048,
//   [2048,4096) read output.  copy_in (LAST) overwrites [0,2048).
//
// XCD placement (T1, verified R4): b = blockIdx.x & 7 pins each batch to one
// XCD; K[b]+Vt[b] (4 MB) / Q[b] (2 MB cached lines) stay L2-resident.
// R6: K/Q/V MFMA fragments are read DIRECTLY from L2 (no LDS staging): the
// glds->LDS->reg path cost a full vmcnt(0) drain at every __syncthreads plus
// LDS write BW; direct per-lane 16B loads feed the B-operand natively.

// ---------------- K1: QKV projection, MFMA GEMM (unchanged, verified) ----------------
__global__ __launch_bounds__(256) void qkv_mfma(
    const float* __restrict__ X,
    const float* __restrict__ Wq, const float* __restrict__ bq,
    const float* __restrict__ Wk, const float* __restrict__ bk,
    const float* __restrict__ Wv, const float* __restrict__ bv,
    u16* __restrict__ outq, u16* __restrict__ Kw, u16* __restrict__ Vt) {
  __shared__ __align__(16) u16 SM[16384];
  u16* As = SM;
  u16* Bs = SM + 8192;
  const int id = blockIdx.x;
  const int xcd = id & 7;
  const int slot = id >> 3;
  const int bxl = slot / 12;
  const int byz = slot - bxl * 12;
  const int z = byz >> 2;
  const int by = byz & 3;
  const int bx = (xcd << 4) + bxl;
  const float* W = (z == 0) ? Wq : ((z == 1) ? Wk : Wv);
  const float* bias = (z == 0) ? bq : ((z == 1) ? bk : bv);
  const int row0 = bx * 128;
  const int col0 = by * 128;
  const int tid = threadIdx.x, lane = tid & 63, w = tid >> 6;
  const int lrow = lane & 15, lg = lane >> 4;
  const int qm = w >> 1, qn = w & 1;
  const int srow = tid >> 1, sh = tid & 1;

  const f32x4 Z4 = {0.f, 0.f, 0.f, 0.f};
  f32x4 acc[4][4];
#pragma unroll
  for (int m = 0; m < 4; ++m)
#pragma unroll
    for (int n = 0; n < 4; ++n) acc[m][n] = Z4;

  const float* Xr = X + (size_t)(row0 + srow) * 512;
  const float* Wr = W + (size_t)(col0 + srow) * 512;

  for (int ks = 0; ks < 8; ++ks) {
    const int k0 = ks * 64;
    __syncthreads();
#pragma unroll
    for (int s4 = 0; s4 < 4; ++s4) {
      const int slt = sh * 4 + s4;
      const int ds = ((slt ^ (srow & 7)) << 3);
      {
        float4 f0 = *(const float4*)(Xr + k0 + slt * 8);
        float4 f1 = *(const float4*)(Xr + k0 + slt * 8 + 4);
        uint4 pk;
        pk.x = cvt2(f0.x, f0.y); pk.y = cvt2(f0.z, f0.w);
        pk.z = cvt2(f1.x, f1.y); pk.w = cvt2(f1.z, f1.w);
        *(uint4*)&As[srow * 64 + ds] = pk;
      }
      {
        float4 f0 = *(const float4*)(Wr + k0 + slt * 8);
        float4 f1 = *(const float4*)(Wr + k0 + slt * 8 + 4);
        uint4 pk;
        pk.x = cvt2(f0.x, f0.y); pk.y = cvt2(f0.z, f0.w);
        pk.z = cvt2(f1.x, f1.y); pk.w = cvt2(f1.z, f1.w);
        *(uint4*)&Bs[srow * 64 + ds] = pk;
      }
    }
    __syncthreads();
#pragma unroll
    for (int cs = 0; cs < 2; ++cs) {
      bf16x8 af[4], bfr[4];
#pragma unroll
      for (int mf = 0; mf < 4; ++mf) {
        const int r = qm * 64 + mf * 16 + lrow;
        af[mf] = *(const bf16x8*)&As[r * 64 + (((cs * 4 + lg) ^ (r & 7)) << 3)];
      }
#pragma unroll
      for (int nf = 0; nf < 4; ++nf) {
        const int r = qn * 64 + nf * 16 + lrow;
        bfr[nf] = *(const bf16x8*)&Bs[r * 64 + (((cs * 4 + lg) ^ (r & 7)) << 3)];
      }
#pragma unroll
      for (int mf = 0; mf < 4; ++mf)
#pragma unroll
        for (int nf = 0; nf < 4; ++nf)
          acc[mf][nf] = MFMA16(af[mf], bfr[nf], acc[mf][nf]);
    }
  }

  if (z < 2) {
    u16* O = (z == 0) ? outq : Kw;
    const int ldo = (z == 0) ? 2048 : 512;
#pragma unroll
    for (int mf = 0; mf < 4; ++mf)
#pragma unroll
      for (int nf = 0; nf < 4; ++nf) {
        const int C = col0 + qn * 64 + nf * 16 + lrow;
        const float bb = bias[C];
#pragma unroll
        for (int r = 0; r < 4; ++r) {
          const int R = row0 + qm * 64 + mf * 16 + lg * 4 + r;
          O[(size_t)R * ldo + C] = f2b(fin(acc[mf][nf][r] + bb));
        }
      }
  } else {
    __syncthreads();
    u16* Tr = SM;  // [128][128]
#pragma unroll
    for (int mf = 0; mf < 4; ++mf)
#pragma unroll
      for (int nf = 0; nf < 4; ++nf) {
        const int vl = qn * 64 + nf * 16 + lrow;
        const float bb = bias[col0 + vl];
#pragma unroll
        for (int r = 0; r < 4; ++r) {
          const int tl = qm * 64 + mf * 16 + lg * 4 + r;
          Tr[vl * 128 + tl] = f2b(fin(acc[mf][nf][r] + bb));
        }
      }
    __syncthreads();
    const int vl = tid >> 1, part = tid & 1;
    const int bI = row0 >> 11;
    u16* dst = Vt + (size_t)(bI * 512 + col0 + vl) * 2048 + (row0 & 2047) + part * 64;
    const u16* sp = &Tr[vl * 128 + part * 64];
#pragma unroll
    for (int q = 0; q < 8; ++q)
      *(uint4*)(dst + q * 8) = *(const uint4*)(sp + q * 8);
  }
}

// ---------------- K2: column denominator partials, barrier-free sweep ----------------
// Grid 512: b = id&7 (XCD pin); rest: py (16 i-tile-pairs of 64 i), stripe (4).
// Two passes: tile py then 31-py.  8 waves = (4 ihh x 2 jq); wave's 16 K-rows
// in regs (A operand).  j-sweep in 32-j windows, stripe takes m = m0+stripe,
// +4...  Q fragments read DIRECT from global (L2).  No LDS, no in-loop
// barriers; per-lane dacc accumulates, one shfl-reduce per pass at the end.
// Writes RAW partial to slot 256+stripe; read_mfma sums the float4.
__global__ __launch_bounds__(512, 4) void denom_mfma(
    const u16* __restrict__ Qs, const u16* __restrict__ Kw, float* __restrict__ rdn) {
  __shared__ float red[4][2][16];
  const int id = blockIdx.x;
  const int b = id & 7, rest = id >> 3;
  const int py = rest >> 2, stripe = rest & 3;
  const int tid = threadIdx.x, lane = tid & 63, w = tid >> 6;
  const int lrow = lane & 15, lg = lane >> 4;
  const int ihh = w >> 1, jq = w & 1;
  const size_t kbase = (size_t)b * 2048 * 512;
  const f32x4 Z4 = {0.f, 0.f, 0.f, 0.f};

  for (int pass = 0; pass < 2; ++pass) {
    const int ti = pass ? (31 - py) : py;
    const int i0 = ti * 64;
    bf16x8 Kf[16];
    const u16* kr = Kw + kbase + (size_t)(i0 + ihh * 16 + lrow) * 512;
#pragma unroll
    for (int cs = 0; cs < 16; ++cs) Kf[cs] = *(const bf16x8*)(kr + cs * 32 + lg * 8);
    float dacc[4] = {0.f, 0.f, 0.f, 0.f};
    const int m0 = (i0 >> 5) + stripe;

    for (int m = m0; m <= 63; m += 4) {
      const u16* qr = Qs + (size_t)(b * 2048 + m * 32 + jq * 16 + lrow) * 2048;
      f32x4 sA = Z4, sB = Z4;
      bf16x8 qf[8];
#pragma unroll
      for (int cs = 0; cs < 8; ++cs) qf[cs] = *(const bf16x8*)(qr + cs * 32 + lg * 8);
#pragma unroll
      for (int cs = 0; cs < 8; ++cs) sA = MFMA16(Kf[cs], qf[cs], sA);
#pragma unroll
      for (int cs = 0; cs < 8; ++cs) qf[cs] = *(const bf16x8*)(qr + (cs + 8) * 32 + lg * 8);
#pragma unroll
      for (int cs = 0; cs < 8; ++cs) sB = MFMA16(Kf[cs + 8], qf[cs], sB);
      // D: col=lane&15 -> j_local; row=lg*4+r -> i_local
      const int jG = m * 32 + jq * 16 + lrow;
      const int ib = i0 + ihh * 16 + lg * 4;
#pragma unroll
      for (int r = 0; r < 4; ++r)
        dacc[r] += (jG >= ib + r) ? expclamp((sA[r] + sB[r]) * SCALE) : 0.f;
    }

    // reduce over the 16 j-lanes (lrow) once per pass
#pragma unroll
    for (int r = 0; r < 4; ++r) {
      float v = dacc[r];
      v += __shfl_xor(v, 1); v += __shfl_xor(v, 2);
      v += __shfl_xor(v, 4); v += __shfl_xor(v, 8);
      if (lrow == 0) red[ihh][jq][lg * 4 + r] = v;
    }
    __syncthreads();
    if (tid < 64) {
      const float d = red[tid >> 4][0][tid & 15] + red[tid >> 4][1][tid & 15];
      rdn[(size_t)(b * 2048 + i0 + tid) * 1024 + 256 + stripe] = d;
    }
    __syncthreads();
  }
}

// ---------------- K3: fused causal read, producer/consumer, no staging ----------------
// Grid 512: b = id&7 (XCD pin); s = id>>3: jt = s<32 ? s : 95-s (balanced
// pairs).  JB=32 j, IW=32 i.  8 waves: role 0 (2jh x 2iq) = QK+exp -> PB[cur];
// role 1 (4 vq x 128 v) = P[prev] x V -> O.  K and V fragments read DIRECT
// from global (L2-resident); LDS holds only the P double-buffer (5 KB).
// One __syncthreads per window; nothing left in flight for it to drain.
__global__ __launch_bounds__(512, 4) void read_mfma(
    const u16* __restrict__ Qs, const u16* __restrict__ Kw, const u16* __restrict__ Vt,
    const float* __restrict__ rdn, float* __restrict__ outf) {
  __shared__ __align__(16) u16 PB[2][32 * 40];  // P[32 j][32 i], stride 40
  const int id = blockIdx.x;
  const int b = id & 7, s = id >> 3;
  const int jt = (s < 32) ? s : 95 - s;
  const int j0 = jt * 32;
  const int tid = threadIdx.x, lane = tid & 63, w = tid >> 6;
  const int lrow = lane & 15, lg = lane >> 4;
  const int role = w >> 2, wq = w & 3;
  const int jh = wq >> 1, iq = wq & 1;  // QK decomposition
  const int vq = wq;                     // PV decomposition
  const int NW = jt + 1;
  const size_t kbase = (size_t)b * 2048 * 512;
  const size_t vbase = (size_t)b * 512 * 2048;
  const f32x4 Z4 = {0.f, 0.f, 0.f, 0.f};

  // RS union: QK waves keep Q fragments (bit-cast bf16x8); PV waves keep O.
  f32x4 RS[16];
  if (role == 0) {
    const u16* qr = Qs + (size_t)(b * 2048 + j0 + jh * 16 + lrow) * 2048;
#pragma unroll
    for (int cs = 0; cs < 16; ++cs)
      RS[cs] = __builtin_bit_cast(f32x4, *(const bf16x8*)(qr + cs * 32 + lg * 8));
  } else {
#pragma unroll
    for (int t = 0; t < 16; ++t) RS[t] = Z4;
  }

  for (int t = 0; t <= NW; ++t) {
    if (role == 0) {
      if (t < NW) {
        const int i0 = t * 32;
        const int iG = i0 + iq * 16 + lrow;
        const float4 rp = *(const float4*)&rdn[(size_t)(b * 2048 + iG) * 1024 + 256];
        // B-operand K fragments direct from L2: lane reads 16B of row iG.
        const u16* kr = Kw + kbase + (size_t)iG * 512;
        f32x4 sA = Z4, sB = Z4;
        bf16x8 kf[8];
#pragma unroll
        for (int cs = 0; cs < 8; ++cs) kf[cs] = *(const bf16x8*)(kr + cs * 32 + lg * 8);
#pragma unroll
        for (int cs = 0; cs < 8; ++cs)
          sA = MFMA16(__builtin_bit_cast(bf16x8, RS[cs]), kf[cs], sA);
#pragma unroll
        for (int cs = 0; cs < 8; ++cs) kf[cs] = *(const bf16x8*)(kr + (cs + 8) * 32 + lg * 8);
#pragma unroll
        for (int cs = 0; cs < 8; ++cs)
          sB = MFMA16(__builtin_bit_cast(bf16x8, RS[cs + 8]), kf[cs], sB);
        const float rd = 1.0f / fmaxf(rp.x + rp.y + rp.z + rp.w, 1e-30f);
        const int jb = j0 + jh * 16 + lg * 4;
#pragma unroll
        for (int r = 0; r < 4; ++r) {
          const float e = (iG <= jb + r) ? expclamp((sA[r] + sB[r]) * SCALE) * rd : 0.f;
          PB[t & 1][(jh * 16 + lg * 4 + r) * 40 + iq * 16 + lrow] = f2b(e);
        }
      }
    } else {
      if (t >= 1) {
        const int i0 = (t - 1) * 32;
        bf16x8 Vp[8];
#pragma unroll
        for (int vt = 0; vt < 8; ++vt)
          Vp[vt] = *(const bf16x8*)(
              Vt + vbase + (size_t)(vq * 128 + vt * 16 + lrow) * 2048 + i0 + lg * 8);
        const u16* pb = &PB[(t - 1) & 1][0];
        const bf16x8 pa0 = *(const bf16x8*)(pb + lrow * 40 + lg * 8);
        const bf16x8 pa1 = *(const bf16x8*)(pb + (16 + lrow) * 40 + lg * 8);
#pragma unroll
        for (int vt = 0; vt < 8; ++vt) {
          RS[vt] = MFMA16(pa0, Vp[vt], RS[vt]);          // j 0..15
          RS[8 + vt] = MFMA16(pa1, Vp[vt], RS[8 + vt]);  // j 16..31
        }
      }
    }
    __syncthreads();  // publishes PB[t&1]
  }

  if (role == 1) {
#pragma unroll
    for (int jh2 = 0; jh2 < 2; ++jh2)
#pragma unroll
      for (int vt = 0; vt < 8; ++vt) {
        const int v = vq * 128 + vt * 16 + lrow;
        const f32x4 o = RS[jh2 * 8 + vt];
#pragma unroll
        for (int r = 0; r < 4; ++r) {
          const int jj = j0 + jh2 * 16 + lg * 4 + r;
          outf[(size_t)(b * 2048 + jj) * 1024 + 512 + v] = fin(o[r]);
        }
      }
  }
}

// ---------------- K4: passthrough fp32 X -> out[:,0:512] (LAST) ----------------
__global__ __launch_bounds__(256) void copy_in_kernel(
    const float* __restrict__ X, float* __restrict__ outf) {
  size_t idx = (size_t)blockIdx.x * 256 + threadIdx.x;
  size_t row = idx >> 7;
  int c = (int)(idx & 127) * 4;
  *(float4*)&outf[row * 1024 + c] = *(const float4*)&X[row * 512 + c];
}

extern "C" void kernel_launch(void* const* d_in, const int* in_sizes, int n_in,
                              void* d_out, int out_size, void* d_ws, size_t ws_size,
                              hipStream_t stream) {
  const float* X  = (const float*)d_in[0];
  const float* Wq = (const float*)d_in[1];
  const float* bq = (const float*)d_in[2];
  const float* Wk = (const float*)d_in[3];
  const float* bk = (const float*)d_in[4];
  const float* Wv = (const float*)d_in[5];
  const float* bv = (const float*)d_in[6];

  char* ws = (char*)d_ws;
  const size_t SZ = (size_t)16384 * 512 * sizeof(u16);
  u16* Kw = (u16*)(ws);
  u16* Vt = (u16*)(ws + SZ);

  qkv_mfma<<<dim3(1536), 256, 0, stream>>>(X, Wq, bq, Wk, bk, Wv, bv,
                                           (u16*)d_out, Kw, Vt);
  denom_mfma<<<dim3(512), 512, 0, stream>>>((const u16*)d_out, Kw, (float*)d_out);
  read_mfma<<<dim3(512), 512, 0, stream>>>((const u16*)d_out, Kw, Vt,
                                           (const float*)d_out, (float*)d_out);
  copy_in_kernel<<<8192, 256, 0, stream>>>(X, (float*)d_out);
}

// Round 9
// 373.389 us; speedup vs baseline: 1.4852x; 1.4852x over previous
//
#include <hip/hip_runtime.h>

typedef unsigned short u16;
using bf16x8 = __attribute__((ext_vector_type(8))) short;
using f32x4  = __attribute__((ext_vector_type(4))) float;

static __device__ __forceinline__ u16 f2b(float f) {
  unsigned int x = __builtin_bit_cast(unsigned int, f);
  unsigned int r = (x + 0x7fffu + ((x >> 16) & 1u)) >> 16;
  return (u16)r;
}
static __device__ __forceinline__ float fin(float x) { return (x != x) ? 0.f : x; }
static __device__ __forceinline__ float expclamp(float x) {
  return __expf(fminf(fmaxf(x, -80.f), 80.f));
}
// packed f32->bf16 RNE convert (same rounding as f2b)
static __device__ __forceinline__ unsigned cvt2(float lo, float hi) {
  unsigned r;
  asm("v_cvt_pk_bf16_f32 %0, %1, %2" : "=v"(r) : "v"(lo), "v"(hi));
  return r;
}

#define SCALE 0.04419417382415922f  // 1/sqrt(512)
#define MFMA16(a, b, c) __builtin_amdgcn_mfma_f32_16x16x32_bf16((a), (b), (c), 0, 0, 0)

static __device__ __forceinline__ void glds16(const u16* g, u16* l) {
  __builtin_amdgcn_global_load_lds(
      (const __attribute__((address_space(1))) unsigned int*)(unsigned long long)(const void*)g,
      (__attribute__((address_space(3))) unsigned int*)(unsigned int)(unsigned long long)(void*)l,
      16, 0, 0);
}

// Memory plan (ws = 33,554,432 B exactly):
//   ws: K bf16 [8][2048][512] @0; Vt bf16 [8][512][2048] (V transposed) @16.78MB
//   d_out per fp32-row r (4096 B): [0,1024) Q bf16 stash (stride 2048 u16),
//   [1024,1040) denom partials f32 x4 (slots 256..259) for column i=r%2048,
//   [2048,4096) read output.  copy_in (LAST) overwrites [0,2048).
//
// Verified levers: XCD pin b=id&7 (R4: FETCH 563->26 MB); glds staging (R6:
// direct scattered L2 fragment loads regress 1.6x); producer/consumer roles +
// RS union (R5).  This round: LPT dispatch order (long blocks first) to kill
// the 1-block/CU tail R5's 26% occupancy revealed; denom with register
// accumulation + one early-issue barrier per window.

// ---------------- K1: QKV projection, MFMA GEMM (unchanged, verified) ----------------
__global__ __launch_bounds__(256) void qkv_mfma(
    const float* __restrict__ X,
    const float* __restrict__ Wq, const float* __restrict__ bq,
    const float* __restrict__ Wk, const float* __restrict__ bk,
    const float* __restrict__ Wv, const float* __restrict__ bv,
    u16* __restrict__ outq, u16* __restrict__ Kw, u16* __restrict__ Vt) {
  __shared__ __align__(16) u16 SM[16384];
  u16* As = SM;
  u16* Bs = SM + 8192;
  const int id = blockIdx.x;
  const int xcd = id & 7;
  const int slot = id >> 3;
  const int bxl = slot / 12;
  const int byz = slot - bxl * 12;
  const int z = byz >> 2;
  const int by = byz & 3;
  const int bx = (xcd << 4) + bxl;
  const float* W = (z == 0) ? Wq : ((z == 1) ? Wk : Wv);
  const float* bias = (z == 0) ? bq : ((z == 1) ? bk : bv);
  const int row0 = bx * 128;
  const int col0 = by * 128;
  const int tid = threadIdx.x, lane = tid & 63, w = tid >> 6;
  const int lrow = lane & 15, lg = lane >> 4;
  const int qm = w >> 1, qn = w & 1;
  const int srow = tid >> 1, sh = tid & 1;

  const f32x4 Z4 = {0.f, 0.f, 0.f, 0.f};
  f32x4 acc[4][4];
#pragma unroll
  for (int m = 0; m < 4; ++m)
#pragma unroll
    for (int n = 0; n < 4; ++n) acc[m][n] = Z4;

  const float* Xr = X + (size_t)(row0 + srow) * 512;
  const float* Wr = W + (size_t)(col0 + srow) * 512;

  for (int ks = 0; ks < 8; ++ks) {
    const int k0 = ks * 64;
    __syncthreads();
#pragma unroll
    for (int s4 = 0; s4 < 4; ++s4) {
      const int slt = sh * 4 + s4;
      const int ds = ((slt ^ (srow & 7)) << 3);
      {
        float4 f0 = *(const float4*)(Xr + k0 + slt * 8);
        float4 f1 = *(const float4*)(Xr + k0 + slt * 8 + 4);
        uint4 pk;
        pk.x = cvt2(f0.x, f0.y); pk.y = cvt2(f0.z, f0.w);
        pk.z = cvt2(f1.x, f1.y); pk.w = cvt2(f1.z, f1.w);
        *(uint4*)&As[srow * 64 + ds] = pk;
      }
      {
        float4 f0 = *(const float4*)(Wr + k0 + slt * 8);
        float4 f1 = *(const float4*)(Wr + k0 + slt * 8 + 4);
        uint4 pk;
        pk.x = cvt2(f0.x, f0.y); pk.y = cvt2(f0.z, f0.w);
        pk.z = cvt2(f1.x, f1.y); pk.w = cvt2(f1.z, f1.w);
        *(uint4*)&Bs[srow * 64 + ds] = pk;
      }
    }
    __syncthreads();
#pragma unroll
    for (int cs = 0; cs < 2; ++cs) {
      bf16x8 af[4], bfr[4];
#pragma unroll
      for (int mf = 0; mf < 4; ++mf) {
        const int r = qm * 64 + mf * 16 + lrow;
        af[mf] = *(const bf16x8*)&As[r * 64 + (((cs * 4 + lg) ^ (r & 7)) << 3)];
      }
#pragma unroll
      for (int nf = 0; nf < 4; ++nf) {
        const int r = qn * 64 + nf * 16 + lrow;
        bfr[nf] = *(const bf16x8*)&Bs[r * 64 + (((cs * 4 + lg) ^ (r & 7)) << 3)];
      }
#pragma unroll
      for (int mf = 0; mf < 4; ++mf)
#pragma unroll
        for (int nf = 0; nf < 4; ++nf)
          acc[mf][nf] = MFMA16(af[mf], bfr[nf], acc[mf][nf]);
    }
  }

  if (z < 2) {
    u16* O = (z == 0) ? outq : Kw;
    const int ldo = (z == 0) ? 2048 : 512;
#pragma unroll
    for (int mf = 0; mf < 4; ++mf)
#pragma unroll
      for (int nf = 0; nf < 4; ++nf) {
        const int C = col0 + qn * 64 + nf * 16 + lrow;
        const float bb = bias[C];
#pragma unroll
        for (int r = 0; r < 4; ++r) {
          const int R = row0 + qm * 64 + mf * 16 + lg * 4 + r;
          O[(size_t)R * ldo + C] = f2b(fin(acc[mf][nf][r] + bb));
        }
      }
  } else {
    __syncthreads();
    u16* Tr = SM;  // [128][128]
#pragma unroll
    for (int mf = 0; mf < 4; ++mf)
#pragma unroll
      for (int nf = 0; nf < 4; ++nf) {
        const int vl = qn * 64 + nf * 16 + lrow;
        const float bb = bias[col0 + vl];
#pragma unroll
        for (int r = 0; r < 4; ++r) {
          const int tl = qm * 64 + mf * 16 + lg * 4 + r;
          Tr[vl * 128 + tl] = f2b(fin(acc[mf][nf][r] + bb));
        }
      }
    __syncthreads();
    const int vl = tid >> 1, part = tid & 1;
    const int bI = row0 >> 11;
    u16* dst = Vt + (size_t)(bI * 512 + col0 + vl) * 2048 + (row0 & 2047) + part * 64;
    const u16* sp = &Tr[vl * 128 + part * 64];
#pragma unroll
    for (int q = 0; q < 8; ++q)
      *(uint4*)(dst + q * 8) = *(const uint4*)(sp + q * 8);
  }
}

// ---------------- K2: column denominator partials ----------------
// Grid 512: b = id&7 (XCD pin); py (16 i-tile-pairs of 64 i) x stripe (4).
// Two passes (py, 31-py).  8 waves = (4 ihh x 2 jq); wave's 16 K-rows in regs.
// j-sweep: 32-j windows m = m0+stripe, +4, ...; Q staged via glds dbuf with
// EARLY issue + ONE __syncthreads per window (drain lands under compute).
// Per-lane reg accumulation; one shfl-reduce per pass.  Partial -> slot
// 256+stripe; read_mfma sums the float4.
__global__ __launch_bounds__(512, 4) void denom_mfma(
    const u16* __restrict__ Qs, const u16* __restrict__ Kw, float* __restrict__ rdn) {
  __shared__ __align__(16) u16 QB[2][16384];  // [32 j][512 c] swizzled
  __shared__ float red[4][2][16];
  const int id = blockIdx.x;
  const int b = id & 7, rest = id >> 3;
  const int py = rest >> 2, stripe = rest & 3;
  const int tid = threadIdx.x, lane = tid & 63, w = tid >> 6;
  const int lrow = lane & 15, lg = lane >> 4;
  const int ihh = w >> 1, jq = w & 1;
  const size_t kbase = (size_t)b * 2048 * 512;
  const f32x4 Z4 = {0.f, 0.f, 0.f, 0.f};

  for (int pass = 0; pass < 2; ++pass) {
    const int ti = pass ? (31 - py) : py;
    const int i0 = ti * 64;
    bf16x8 Kf[16];
    const u16* kr = Kw + kbase + (size_t)(i0 + ihh * 16 + lrow) * 512;
#pragma unroll
    for (int cs = 0; cs < 16; ++cs) Kf[cs] = *(const bf16x8*)(kr + cs * 32 + lg * 8);
    float dacc[4] = {0.f, 0.f, 0.f, 0.f};
    const int m0 = (i0 >> 5) + stripe;

    if (m0 <= 63) {
#pragma unroll
      for (int p = 0; p < 4; ++p) {  // prologue stage: 32 rows / 8 waves
        const int row = p * 8 + w;
        glds16(Qs + (size_t)(b * 2048 + m0 * 32 + row) * 2048 + ((lane ^ (row & 7)) << 3),
               &QB[0][row * 512]);
      }
    }
    __syncthreads();

    int n = 0;
    for (int m = m0; m <= 63; m += 4, ++n) {
      const int cur = n & 1;
      if (m + 4 <= 63) {  // EARLY issue of next window's staging
#pragma unroll
        for (int p = 0; p < 4; ++p) {
          const int row = p * 8 + w;
          glds16(Qs + (size_t)(b * 2048 + (m + 4) * 32 + row) * 2048 + ((lane ^ (row & 7)) << 3),
                 &QB[cur ^ 1][row * 512]);
        }
      }
      const u16* qb = &QB[cur][0];
      const int qrow = jq * 16 + lrow;
      f32x4 sA = Z4, sB = Z4;
      bf16x8 qf[8];
#pragma unroll
      for (int cs = 0; cs < 8; ++cs)
        qf[cs] = *(const bf16x8*)(qb + qrow * 512 + (((cs * 4 + lg) ^ (lrow & 7)) << 3));
#pragma unroll
      for (int cs = 0; cs < 8; ++cs) sA = MFMA16(Kf[cs], qf[cs], sA);
#pragma unroll
      for (int cs = 0; cs < 8; ++cs)
        qf[cs] = *(const bf16x8*)(qb + qrow * 512 + ((((cs + 8) * 4 + lg) ^ (lrow & 7)) << 3));
#pragma unroll
      for (int cs = 0; cs < 8; ++cs) sB = MFMA16(Kf[cs + 8], qf[cs], sB);
      // D: col=lane&15 -> j_local; row=lg*4+r -> i_local
      const int jG = m * 32 + jq * 16 + lrow;
      const int ib = i0 + ihh * 16 + lg * 4;
#pragma unroll
      for (int r = 0; r < 4; ++r)
        dacc[r] += (jG >= ib + r) ? expclamp((sA[r] + sB[r]) * SCALE) : 0.f;
      __syncthreads();  // publishes QB[cur^1]; glds issued early -> cheap drain
    }

    // reduce over the 16 j-lanes (lrow) once per pass
#pragma unroll
    for (int r = 0; r < 4; ++r) {
      float v = dacc[r];
      v += __shfl_xor(v, 1); v += __shfl_xor(v, 2);
      v += __shfl_xor(v, 4); v += __shfl_xor(v, 8);
      if (lrow == 0) red[ihh][jq][lg * 4 + r] = v;
    }
    __syncthreads();
    if (tid < 64) {
      const float d = red[tid >> 4][0][tid & 15] + red[tid >> 4][1][tid & 15];
      rdn[(size_t)(b * 2048 + i0 + tid) * 1024 + 256 + stripe] = d;
    }
    __syncthreads();
  }
}

// ---------------- K3: fused causal read, producer/consumer, LPT order ----------------
// Grid 512: b = id&7 (XCD pin); k = id>>3: jt = k<32 ? 63-k : k-32 -- LONG
// blocks dispatch first (LPT), shorts fill second resident slots; pair sums
// stay 65 windows/CU.  JB=32 j, IW=32 i.  8 waves: role 0 (2jh x 2iq) =
// QK+exp -> PB[cur]; role 1 (4 vq x 128 v) = P[prev] x V -> O.  K via glds
// dbuf (early issue).  Identical loop body to the R5-passing kernel; only the
// jt mapping changed.
__global__ __launch_bounds__(512, 4) void read_mfma(
    const u16* __restrict__ Qs, const u16* __restrict__ Kw, const u16* __restrict__ Vt,
    const float* __restrict__ rdn, float* __restrict__ outf) {
  __shared__ __align__(16) u16 KB[2][16384];  // [32 i][512 c] swizzled
  __shared__ __align__(16) u16 PB[2][32 * 40];  // P[32 j][32 i], stride 40
  const int id = blockIdx.x;
  const int b = id & 7, k = id >> 3;
  const int jt = (k < 32) ? (63 - k) : (k - 32);  // LPT: long first
  const int j0 = jt * 32;
  const int tid = threadIdx.x, lane = tid & 63, w = tid >> 6;
  const int lrow = lane & 15, lg = lane >> 4;
  const int role = w >> 2, wq = w & 3;
  const int jh = wq >> 1, iq = wq & 1;  // QK decomposition
  const int vq = wq;                     // PV decomposition
  const int NW = jt + 1;
  const size_t kbase = (size_t)b * 2048 * 512;
  const size_t vbase = (size_t)b * 512 * 2048;
  const f32x4 Z4 = {0.f, 0.f, 0.f, 0.f};

  // RS union: QK waves keep Q fragments (bit-cast bf16x8); PV waves keep O.
  f32x4 RS[16];
  if (role == 0) {
    const u16* qr = Qs + (size_t)(b * 2048 + j0 + jh * 16 + lrow) * 2048;
#pragma unroll
    for (int cs = 0; cs < 16; ++cs)
      RS[cs] = __builtin_bit_cast(f32x4, *(const bf16x8*)(qr + cs * 32 + lg * 8));
  } else {
#pragma unroll
    for (int t = 0; t < 16; ++t) RS[t] = Z4;
  }

#pragma unroll
  for (int p = 0; p < 4; ++p) {  // prologue: stage window 0
    const int row = p * 8 + w;
    glds16(Kw + kbase + (size_t)row * 512 + ((lane ^ (row & 7)) << 3),
           &KB[0][row * 512]);
  }
  __syncthreads();

  for (int t = 0; t <= NW; ++t) {
    if (t + 1 < NW) {  // EARLY issue next window's staging
#pragma unroll
      for (int p = 0; p < 4; ++p) {
        const int row = p * 8 + w;
        glds16(Kw + kbase + (size_t)((t + 1) * 32 + row) * 512 + ((lane ^ (row & 7)) << 3),
               &KB[(t + 1) & 1][row * 512]);
      }
    }
    if (role == 0) {
      if (t < NW) {
        const int i0 = t * 32;
        const int iG = i0 + iq * 16 + lrow;
        const float4 rp = *(const float4*)&rdn[(size_t)(b * 2048 + iG) * 1024 + 256];
        const u16* kb = &KB[t & 1][0];
        const int krow = iq * 16 + lrow;
        f32x4 sA = Z4, sB = Z4;
        bf16x8 kf[8];
#pragma unroll
        for (int cs = 0; cs < 8; ++cs)
          kf[cs] = *(const bf16x8*)(kb + krow * 512 + (((cs * 4 + lg) ^ (lrow & 7)) << 3));
#pragma unroll
        for (int cs = 0; cs < 8; ++cs)
          sA = MFMA16(__builtin_bit_cast(bf16x8, RS[cs]), kf[cs], sA);
#pragma unroll
        for (int cs = 0; cs < 8; ++cs)
          kf[cs] = *(const bf16x8*)(kb + krow * 512 + (((32 + cs * 4 + lg) ^ (lrow & 7)) << 3));
#pragma unroll
        for (int cs = 0; cs < 8; ++cs)
          sB = MFMA16(__builtin_bit_cast(bf16x8, RS[cs + 8]), kf[cs], sB);
        const float rd = 1.0f / fmaxf(rp.x + rp.y + rp.z + rp.w, 1e-30f);
        const int jb = j0 + jh * 16 + lg * 4;
#pragma unroll
        for (int r = 0; r < 4; ++r) {
          const float e = (iG <= jb + r) ? expclamp((sA[r] + sB[r]) * SCALE) * rd : 0.f;
          PB[t & 1][(jh * 16 + lg * 4 + r) * 40 + iq * 16 + lrow] = f2b(e);
        }
      }
    } else {
      if (t >= 1) {
        const int i0 = (t - 1) * 32;
        bf16x8 Vp[8];
#pragma unroll
        for (int vt = 0; vt < 8; ++vt)
          Vp[vt] = *(const bf16x8*)(
              Vt + vbase + (size_t)(vq * 128 + vt * 16 + lrow) * 2048 + i0 + lg * 8);
        const u16* pb = &PB[(t - 1) & 1][0];
        const bf16x8 pa0 = *(const bf16x8*)(pb + lrow * 40 + lg * 8);
        const bf16x8 pa1 = *(const bf16x8*)(pb + (16 + lrow) * 40 + lg * 8);
#pragma unroll
        for (int vt = 0; vt < 8; ++vt) {
          RS[vt] = MFMA16(pa0, Vp[vt], RS[vt]);          // j 0..15
          RS[8 + vt] = MFMA16(pa1, Vp[vt], RS[8 + vt]);  // j 16..31
        }
      }
    }
    __syncthreads();  // publishes PB[t&1]; KB glds issued early -> cheap drain
  }

  if (role == 1) {
#pragma unroll
    for (int jh2 = 0; jh2 < 2; ++jh2)
#pragma unroll
      for (int vt = 0; vt < 8; ++vt) {
        const int v = vq * 128 + vt * 16 + lrow;
        const f32x4 o = RS[jh2 * 8 + vt];
#pragma unroll
        for (int r = 0; r < 4; ++r) {
          const int jj = j0 + jh2 * 16 + lg * 4 + r;
          outf[(size_t)(b * 2048 + jj) * 1024 + 512 + v] = fin(o[r]);
        }
      }
  }
}

// ---------------- K4: passthrough fp32 X -> out[:,0:512] (LAST) ----------------
__global__ __launch_bounds__(256) void copy_in_kernel(
    const float* __restrict__ X, float* __restrict__ outf) {
  size_t idx = (size_t)blockIdx.x * 256 + threadIdx.x;
  size_t row = idx >> 7;
  int c = (int)(idx & 127) * 4;
  *(float4*)&outf[row * 1024 + c] = *(const float4*)&X[row * 512 + c];
}

extern "C" void kernel_launch(void* const* d_in, const int* in_sizes, int n_in,
                              void* d_out, int out_size, void* d_ws, size_t ws_size,
                              hipStream_t stream) {
  const float* X  = (const float*)d_in[0];
  const float* Wq = (const float*)d_in[1];
  const float* bq = (const float*)d_in[2];
  const float* Wk = (const float*)d_in[3];
  const float* bk = (const float*)d_in[4];
  const float* Wv = (const float*)d_in[5];
  const float* bv = (const float*)d_in[6];

  char* ws = (char*)d_ws;
  const size_t SZ = (size_t)16384 * 512 * sizeof(u16);
  u16* Kw = (u16*)(ws);
  u16* Vt = (u16*)(ws + SZ);

  qkv_mfma<<<dim3(1536), 256, 0, stream>>>(X, Wq, bq, Wk, bk, Wv, bv,
                                           (u16*)d_out, Kw, Vt);
  denom_mfma<<<dim3(512), 512, 0, stream>>>((const u16*)d_out, Kw, (float*)d_out);
  read_mfma<<<dim3(512), 512, 0, stream>>>((const u16*)d_out, Kw, Vt,
                                           (const float*)d_out, (float*)d_out);
  copy_in_kernel<<<8192, 256, 0, stream>>>(X, (float*)d_out);
}